// Round 2
// baseline (867.918 us; speedup 1.0000x reference)
//
#include <hip/hip_runtime.h>
#include <hip/hip_bf16.h>
#include <math.h>

// B=8, T=2048, N_EMBED=1024, G_HEAD=8, V_CLUSTER=512, HEAD_SIZE=128. N=B*T=16384.
#define GHEAD 8
#define VCLUSTER 512
#define HSIZE 128
#define NQ 16384
#define NEMBED 1024

// Kernel 1: per-codeword squared norms -> d_ws (4096 floats).
__global__ __launch_bounds__(256) void pq_norms_kernel(const float* __restrict__ embed,
                                                       float* __restrict__ norms) {
    int v = blockIdx.x * 256 + threadIdx.x;   // 0..4095 (8*512)
    const float4* e = reinterpret_cast<const float4*>(embed + (size_t)v * HSIZE);
    float ax = 0.f, ay = 0.f, az = 0.f, aw = 0.f;
#pragma unroll
    for (int i = 0; i < HSIZE / 4; ++i) {
        float4 ev = e[i];
        ax = fmaf(ev.x, ev.x, ax);
        ay = fmaf(ev.y, ev.y, ay);
        az = fmaf(ev.z, ev.z, az);
        aw = fmaf(ev.w, ev.w, aw);
    }
    norms[v] = (ax + ay) + (az + aw);
}

// Kernel 2: one lane = one (query, group). Query (128 f32) in VGPRs; codeword
// stream is wave-uniform. fp32 pass tracks top-2; close calls re-ranked in fp64.
__global__ __launch_bounds__(256, 2) void pq_main_kernel(const float* __restrict__ x,
                                                         const float* __restrict__ embed,
                                                         const float* __restrict__ norms,
                                                         float* __restrict__ out_q,
                                                         float* __restrict__ out_c) {
    int wv = (int)((blockIdx.x * 256u + threadIdx.x) >> 6);   // global wave id 0..2047
    wv = __builtin_amdgcn_readfirstlane(wv);                  // SGPR: uniform codeword addressing
    const int lane  = (int)(threadIdx.x & 63);
    const int g     = wv >> 8;            // 0..7
    const int nbase = (wv & 255) * 64;
    const int n     = nbase + lane;       // 0..16383

    const float4* xp = reinterpret_cast<const float4*>(x + (size_t)n * NEMBED + g * HSIZE);
    float4 xr[32];
#pragma unroll
    for (int i = 0; i < 32; ++i) xr[i] = xp[i];

    // ||x||^2, 4 independent chains
    float ax = 0.f, ay = 0.f, az = 0.f, aw = 0.f;
#pragma unroll
    for (int i = 0; i < 32; ++i) {
        ax = fmaf(xr[i].x, xr[i].x, ax);
        ay = fmaf(xr[i].y, xr[i].y, ay);
        az = fmaf(xr[i].z, xr[i].z, az);
        aw = fmaf(xr[i].w, xr[i].w, aw);
    }
    const float xn2 = (ax + ay) + (az + aw);

    const float* eg = embed + (size_t)g * VCLUSTER * HSIZE;   // uniform
    const float* ng = norms + g * VCLUSTER;                   // uniform

    // fp32 pass with top-2 tracking
    float m1 = INFINITY, m2 = INFINITY;
    int   i1 = 0, i2 = 0;
#pragma unroll 2
    for (int v = 0; v < VCLUSTER; ++v) {
        const float4* ev = reinterpret_cast<const float4*>(eg + v * HSIZE); // uniform addr
        float cx = 0.f, cy = 0.f, cz = 0.f, cw = 0.f;
#pragma unroll
        for (int i = 0; i < 32; ++i) {
            float4 e4 = ev[i];
            cx = fmaf(xr[i].x, e4.x, cx);
            cy = fmaf(xr[i].y, e4.y, cy);
            cz = fmaf(xr[i].z, e4.z, cz);
            cw = fmaf(xr[i].w, e4.w, cw);
        }
        float dot = (cx + cy) + (cz + cw);
        float d2 = fmaf(-2.0f, dot, xn2 + ng[v]);
        bool b1 = d2 < m1;                 // strict '<' = numpy first-index tie-break
        bool b2 = d2 < m2;
        // shift old best into slot 2 when displaced
        m2 = b1 ? m1 : (b2 ? d2 : m2);
        i2 = b1 ? i1 : (b2 ? v  : i2);
        m1 = b1 ? d2 : m1;
        i1 = b1 ? v  : i1;
    }

    int best_i = i1;
    // fp64 refinement when top-2 are inside fp32 noise (wave-level branch: no divergence)
    if (__any((m2 - m1) < 0.25f)) {
        const float4* e1p = reinterpret_cast<const float4*>(eg + (size_t)i1 * HSIZE);
        const float4* e2p = reinterpret_cast<const float4*>(eg + (size_t)i2 * HSIZE);
        double s1a = 0.0, s1b = 0.0, s2a = 0.0, s2b = 0.0;
#pragma unroll 4
        for (int i = 0; i < 32; ++i) {
            float4 e4 = e1p[i];
            double dx = (double)xr[i].x - (double)e4.x;
            double dy = (double)xr[i].y - (double)e4.y;
            double dz = (double)xr[i].z - (double)e4.z;
            double dw = (double)xr[i].w - (double)e4.w;
            s1a = fma(dx, dx, s1a); s1b = fma(dy, dy, s1b);
            s1a = fma(dz, dz, s1a); s1b = fma(dw, dw, s1b);
        }
#pragma unroll 4
        for (int i = 0; i < 32; ++i) {
            float4 e4 = e2p[i];
            double dx = (double)xr[i].x - (double)e4.x;
            double dy = (double)xr[i].y - (double)e4.y;
            double dz = (double)xr[i].z - (double)e4.z;
            double dw = (double)xr[i].w - (double)e4.w;
            s2a = fma(dx, dx, s2a); s2b = fma(dy, dy, s2b);
            s2a = fma(dz, dz, s2a); s2b = fma(dw, dw, s2b);
        }
        double d1 = s1a + s1b;
        double d2 = s2a + s2b;
        // pick true smaller; exact tie -> smaller index (numpy argmin semantics)
        bool pick2 = (d2 < d1) || (d2 == d1 && i2 < i1);
        best_i = pick2 ? i2 : i1;
    }

    // quantize output: copy winning codeword (L2-hot)
    const float4* eb = reinterpret_cast<const float4*>(eg + (size_t)best_i * HSIZE);
    float4* qo = reinterpret_cast<float4*>(out_q + (size_t)n * NEMBED + g * HSIZE);
#pragma unroll
    for (int i = 0; i < 32; ++i) qo[i] = eb[i];

    out_c[(size_t)n * GHEAD + g] = (float)best_i;
}

extern "C" void kernel_launch(void* const* d_in, const int* in_sizes, int n_in,
                              void* d_out, int out_size, void* d_ws, size_t ws_size,
                              hipStream_t stream) {
    const float* x     = (const float*)d_in[0];   // (8, 2048, 1024) f32
    const float* embed = (const float*)d_in[1];   // (8, 512, 128)  f32
    float* out_q = (float*)d_out;                 // quantize: 16,777,216 f32
    float* out_c = out_q + (size_t)NQ * NEMBED;   // codes (stored as f32)
    float* norms = (float*)d_ws;                  // 4096 f32 scratch

    pq_norms_kernel<<<16, 256, 0, stream>>>(embed, norms);
    pq_main_kernel<<<512, 256, 0, stream>>>(x, embed, norms, out_q, out_c);
}